// Round 10
// baseline (113.968 us; speedup 1.0000x reference)
//
#include <hip/hip_runtime.h>
#include <hip/hip_bf16.h>
#include <stdint.h>

#define SEQ 4096
#define EMB 1024
#define HD  64
#define NB  4

typedef __attribute__((ext_vector_type(8))) short short8;   // 8 x bf16 (4 VGPRs)
typedef __attribute__((ext_vector_type(4))) float f32x4;
typedef __attribute__((ext_vector_type(4))) unsigned int uint4v;

// RNE float -> bf16 bits (no NaN inputs here)
static __device__ __forceinline__ unsigned short f2bf(float f) {
    unsigned int u = __float_as_uint(f);
    u += 0x7fffu + ((u >> 16) & 1u);
    return (unsigned short)(u >> 16);
}

// ---------------------------------------------------------------------------
// Prep: Wt[m][d][e] = bf16(W_m[e][d]),  m in {q,k,v}.  3*64*1024 elements.
// Wq is pre-scaled by log2(e)/sqrt(64) so attn needs no scale multiply.
// ---------------------------------------------------------------------------
__global__ __launch_bounds__(256) void wprep_kernel(
        const float* __restrict__ Wq, const float* __restrict__ Wk,
        const float* __restrict__ Wv, unsigned short* __restrict__ Wt) {
    int idx = blockIdx.x * 256 + threadIdx.x;       // < 3*65536
    int m = idx >> 16;
    int r = idx & 65535;
    int d = r >> 10;
    int e = r & 1023;
    const float* W = (m == 0) ? Wq : (m == 1) ? Wk : Wv;
    float v = W[e * HD + d];
    if (m == 0) v *= 0.18033688011111793f;          // log2(e)/sqrt(64)
    Wt[idx] = f2bf(v);
}

// ---------------------------------------------------------------------------
// QKV projection: 32-row blocks, fused m, 4-wave K-split (256 K each, 8 steps).
// (unchanged from R7/R8 — this round isolates the attn change)
// ---------------------------------------------------------------------------
__global__ __launch_bounds__(256, 2) void qkv_kernel(
        const float* __restrict__ H, const unsigned short* __restrict__ Wt,
        unsigned short* __restrict__ Qb, unsigned short* __restrict__ Kb,
        unsigned short* __restrict__ Vt) {
    __shared__ float lds_red[2][32][192];   // 48 KB
    const int tid  = threadIdx.x;
    const int wid  = tid >> 6;
    const int lane = tid & 63;
    const int lr = lane & 15, lg = lane >> 4;
    const int rowbase = blockIdx.x * 32;

    const float* __restrict__ a0p = H + (size_t)(rowbase + lr) * EMB + wid * 256 + lg * 8;
    const float* __restrict__ a1p = a0p + 16 * EMB;
    const unsigned short* __restrict__ wb = Wt + wid * 256 + lg * 8;

    f32x4 acc[2][3][4];
    #pragma unroll
    for (int rt = 0; rt < 2; ++rt)
        #pragma unroll
        for (int m = 0; m < 3; ++m)
            #pragma unroll
            for (int nt = 0; nt < 4; ++nt)
                acc[rt][m][nt] = f32x4{0.f, 0.f, 0.f, 0.f};

    f32x4 hA0, hA1, hA2, hA3, hB0, hB1, hB2, hB3;

    auto compute_step = [&](f32x4& h0, f32x4& h1, f32x4& h2, f32x4& h3, int kk) {
        short8 af0, af1;
        #pragma unroll
        for (int j = 0; j < 4; ++j) {
            af0[j]     = (short)f2bf(h0[j]);
            af0[4 + j] = (short)f2bf(h1[j]);
            af1[j]     = (short)f2bf(h2[j]);
            af1[4 + j] = (short)f2bf(h3[j]);
        }
        #pragma unroll
        for (int m = 0; m < 3; ++m) {
            #pragma unroll
            for (int nt = 0; nt < 4; ++nt) {
                short8 bf_ = *(const short8*)(wb + m * 65536 + (nt * 16 + lr) * EMB + kk);
                acc[0][m][nt] = __builtin_amdgcn_mfma_f32_16x16x32_bf16(af0, bf_, acc[0][m][nt], 0, 0, 0);
                acc[1][m][nt] = __builtin_amdgcn_mfma_f32_16x16x32_bf16(af1, bf_, acc[1][m][nt], 0, 0, 0);
            }
        }
    };

    // prologue: load kk=0
    hA0 = *(const f32x4*)(a0p);  hA1 = *(const f32x4*)(a0p + 4);
    hA2 = *(const f32x4*)(a1p);  hA3 = *(const f32x4*)(a1p + 4);

    #pragma unroll
    for (int kko = 0; kko < 4; ++kko) {
        const int kk = kko * 64;
        hB0 = *(const f32x4*)(a0p + kk + 32);  hB1 = *(const f32x4*)(a0p + kk + 36);
        hB2 = *(const f32x4*)(a1p + kk + 32);  hB3 = *(const f32x4*)(a1p + kk + 36);
        compute_step(hA0, hA1, hA2, hA3, kk);
        if (kko < 3) {
            hA0 = *(const f32x4*)(a0p + kk + 64);  hA1 = *(const f32x4*)(a0p + kk + 68);
            hA2 = *(const f32x4*)(a1p + kk + 64);  hA3 = *(const f32x4*)(a1p + kk + 68);
        }
        compute_step(hB0, hB1, hB2, hB3, kk + 32);
    }

    // ---- pairwise cross-wave reduction
    if (wid >= 2) {
        #pragma unroll
        for (int rt = 0; rt < 2; ++rt)
            #pragma unroll
            for (int m = 0; m < 3; ++m)
                #pragma unroll
                for (int nt = 0; nt < 4; ++nt)
                    #pragma unroll
                    for (int r = 0; r < 4; ++r)
                        lds_red[wid - 2][rt * 16 + lg * 4 + r][m * 64 + nt * 16 + lr] = acc[rt][m][nt][r];
    }
    __syncthreads();
    if (wid < 2) {
        #pragma unroll
        for (int rt = 0; rt < 2; ++rt)
            #pragma unroll
            for (int m = 0; m < 3; ++m)
                #pragma unroll
                for (int nt = 0; nt < 4; ++nt)
                    #pragma unroll
                    for (int r = 0; r < 4; ++r)
                        acc[rt][m][nt][r] += lds_red[wid][rt * 16 + lg * 4 + r][m * 64 + nt * 16 + lr];
    }
    __syncthreads();
    if (wid == 1) {
        #pragma unroll
        for (int rt = 0; rt < 2; ++rt)
            #pragma unroll
            for (int m = 0; m < 3; ++m)
                #pragma unroll
                for (int nt = 0; nt < 4; ++nt)
                    #pragma unroll
                    for (int r = 0; r < 4; ++r)
                        lds_red[0][rt * 16 + lg * 4 + r][m * 64 + nt * 16 + lr] = acc[rt][m][nt][r];
    }
    __syncthreads();
    if (wid == 0) {
        #pragma unroll
        for (int rt = 0; rt < 2; ++rt)
            #pragma unroll
            for (int m = 0; m < 3; ++m)
                #pragma unroll
                for (int nt = 0; nt < 4; ++nt)
                    #pragma unroll
                    for (int r = 0; r < 4; ++r) {
                        int row = rt * 16 + lg * 4 + r;
                        int col = m * 64 + nt * 16 + lr;
                        lds_red[0][row][col] += acc[rt][m][nt][r];
                    }
    }
    __syncthreads();

    // ---- parallel epilogue: 256 threads store from lds_red[0]
    {
        const int row = tid >> 3;            // 0..31
        const int d0  = (tid & 7) * 8;       // 0,8,...,56
        const size_t grow = (size_t)(rowbase + row);
        short8 uq, uk;
        #pragma unroll
        for (int j = 0; j < 8; ++j) {
            uq[j] = (short)f2bf(lds_red[0][row][d0 + j]);
            uk[j] = (short)f2bf(lds_red[0][row][64 + d0 + j]);
        }
        *(short8*)(Qb + grow * HD + d0) = uq;
        *(short8*)(Kb + grow * HD + d0) = uk;
    }
    {
        const int d  = tid >> 2;             // 0..63
        const int j  = tid & 3;
        const int b  = rowbase >> 12;
        const int sl = rowbase & (SEQ - 1);
        unsigned short* vrow = Vt + ((size_t)b * HD + d) * SEQ + sl;
        #pragma unroll
        for (int k4 = 0; k4 < 4; ++k4) {
            int t0 = j * 2 + k4 * 8;         // even t in 0..30
            int p0 = ((t0 & 12) << 1) | (t0 & 3) | ((t0 & 16) >> 2);
            unsigned int val = (unsigned int)f2bf(lds_red[0][t0][128 + d])
                             | ((unsigned int)f2bf(lds_red[0][t0 + 1][128 + d]) << 16);
            *(unsigned int*)(vrow + p0) = val;
        }
    }
}

// ---------------------------------------------------------------------------
// Flash attention, causal, split-K within a block, SWAPPED QK^T, KVBLK=64.
// All 16 K+V loads of a 64-key chunk are issued up-front (one latency round);
// __launch_bounds__(512,4) gives 128-VGPR headroom to keep them in flight.
// PER-LANE softmax state: each lane tracks (mrun,lrun) over ITS 16 keys ->
// ZERO cross-lane ops in the loop. The cross-wave LDS merge reconciles
// 8 waves x 4 lane-groups partials (per-column weight via lg(d)=(d>>2)&3).
// mrun init = 0 (not -inf): fully-masked lanes produce p=exp2(-1e30)=0.
// P packed with v_cvt_pk_bf16_f32 (1 instr / 2 values).
// Defer-max (THR=8 in exp2 domain, wave vote). Q pre-scaled in wprep.
// ---------------------------------------------------------------------------
__global__ __launch_bounds__(512, 4) void attn_kernel(
        const unsigned short* __restrict__ Qb, const unsigned short* __restrict__ Kb,
        const unsigned short* __restrict__ Vt, float* __restrict__ out) {
    __shared__ float lds_o[8][16][65];     // 33.3 KB partials (padded)
    __shared__ float lds_ml[8][4][16][2];  // 4 KB per-(wave,lanegroup) m,l
    const int tid  = threadIdx.x;
    const int w    = tid >> 6;
    const int lane = tid & 63;
    const int lr = lane & 15, lg = lane >> 4;

    const int bid  = blockIdx.x;
    const int xcd  = bid & 7;              // dispatch round-robins XCDs
    const int slot = bid >> 3;             // 0..127 within this XCD
    const int b    = xcd & 3;              // batch pinned to XCD
    const int pz   = slot & 31, hh = slot >> 5;
    const int qtl  = (hh << 5) | ((hh & 1) ? (31 - pz) : pz);  // per-CU balance
    const int qt   = (qtl << 1) | (xcd >> 2);
    const int qbase = qt * 16;

    const unsigned short* __restrict__ Qp = Qb + ((size_t)b * SEQ + qbase) * HD;
    const unsigned short* __restrict__ Kp = Kb + (size_t)b * SEQ * HD;
    const unsigned short* __restrict__ Vp = Vt + (size_t)b * HD * SEQ;

    short8 qf0 = *(const short8*)(Qp + lr * HD +      lg * 8);
    short8 qf1 = *(const short8*)(Qp + lr * HD + 32 + lg * 8);

    f32x4 o[4];
    #pragma unroll
    for (int nt = 0; nt < 4; ++nt) o[nt] = f32x4{0.f, 0.f, 0.f, 0.f};
    float mrun = 0.f;                       // per-lane running max (exp2 domain)
    float lrun = 0.f;

    const int total64 = (qbase + 79) >> 6;  // ceil((qbase+16)/64) chunks

    for (int it = w; it < total64; it += 8) {
        const int kvb = it * 64;
        const unsigned short* kp = Kp + (size_t)(kvb + lr) * HD + lg * 8;
        const unsigned short* vp = Vp + (size_t)lr * SEQ + kvb + lg * 8;

        // ---- issue ALL 16 loads up-front (one latency round)
        short8 k00 = *(const short8*)(kp);
        short8 k01 = *(const short8*)(kp + 32);
        short8 k10 = *(const short8*)(kp + 16 * HD);
        short8 k11 = *(const short8*)(kp + 16 * HD + 32);
        short8 k20 = *(const short8*)(kp + 32 * HD);
        short8 k21 = *(const short8*)(kp + 32 * HD + 32);
        short8 k30 = *(const short8*)(kp + 48 * HD);
        short8 k31 = *(const short8*)(kp + 48 * HD + 32);
        short8 vf00 = *(const short8*)(vp);
        short8 vf01 = *(const short8*)(vp + 32);
        short8 vf10 = *(const short8*)(vp + 16 * SEQ);
        short8 vf11 = *(const short8*)(vp + 16 * SEQ + 32);
        short8 vf20 = *(const short8*)(vp + 32 * SEQ);
        short8 vf21 = *(const short8*)(vp + 32 * SEQ + 32);
        short8 vf30 = *(const short8*)(vp + 48 * SEQ);
        short8 vf31 = *(const short8*)(vp + 48 * SEQ + 32);

        // ---- QK^T (swapped): s_t[q] for keys kvb + t*16 + lg*4 + r
        f32x4 s0 = f32x4{0.f, 0.f, 0.f, 0.f};
        f32x4 s1 = f32x4{0.f, 0.f, 0.f, 0.f};
        f32x4 s2 = f32x4{0.f, 0.f, 0.f, 0.f};
        f32x4 s3 = f32x4{0.f, 0.f, 0.f, 0.f};
        s0 = __builtin_amdgcn_mfma_f32_16x16x32_bf16(k00, qf0, s0, 0, 0, 0);
        s0 = __builtin_amdgcn_mfma_f32_16x16x32_bf16(k01, qf1, s0, 0, 0, 0);
        s1 = __builtin_amdgcn_mfma_f32_16x16x32_bf16(k10, qf0, s1, 0, 0, 0);
        s1 = __builtin_amdgcn_mfma_f32_16x16x32_bf16(k11, qf1, s1, 0, 0, 0);
        s2 = __builtin_amdgcn_mfma_f32_16x16x32_bf16(k20, qf0, s2, 0, 0, 0);
        s2 = __builtin_amdgcn_mfma_f32_16x16x32_bf16(k21, qf1, s2, 0, 0, 0);
        s3 = __builtin_amdgcn_mfma_f32_16x16x32_bf16(k30, qf0, s3, 0, 0, 0);
        s3 = __builtin_amdgcn_mfma_f32_16x16x32_bf16(k31, qf1, s3, 0, 0, 0);

        if (kvb + 63 > qbase) {            // chunk touches the diagonal
            const int qg = qbase + lr;
            #pragma unroll
            for (int r = 0; r < 4; ++r) {
                int ky = kvb + lg * 4 + r;
                if (ky      > qg) s0[r] = -1e30f;
                if (ky + 16 > qg) s1[r] = -1e30f;
                if (ky + 32 > qg) s2[r] = -1e30f;
                if (ky + 48 > qg) s3[r] = -1e30f;
            }
        }

        // ---- per-lane max over this lane's 16 keys (no cross-lane ops)
        float m01 = fmaxf(fmaxf(s0[0], s0[1]), fmaxf(s0[2], s0[3]));
        float m23 = fmaxf(fmaxf(s1[0], s1[1]), fmaxf(s1[2], s1[3]));
        float m45 = fmaxf(fmaxf(s2[0], s2[1]), fmaxf(s2[2], s2[3]));
        float m67 = fmaxf(fmaxf(s3[0], s3[1]), fmaxf(s3[2], s3[3]));
        float mx = fmaxf(fmaxf(m01, m23), fmaxf(m45, m67));

        // defer-max: rescale only when some lane's max grew by more than 8
        if (!__all(mx <= mrun + 8.f)) {
            float mnew = fmaxf(mrun, mx);
            float f = exp2f(mrun - mnew);
            mrun = mnew;
            lrun *= f;
            #pragma unroll
            for (int nt = 0; nt < 4; ++nt) o[nt] *= f;
        }

        // ---- P = exp2(s - mrun), pack pairs with v_cvt_pk_bf16_f32
        float p0[4], p1[4], p2[4], p3[4];
        #pragma unroll
        for (int r = 0; r < 4; ++r) {
            p0[r] = exp2f(s0[r] - mrun);
            p1[r] = exp2f(s1[r] - mrun);
            p2[r] = exp2f(s2[r] - mrun);
            p3[r] = exp2f(s3[r] - mrun);
        }
        lrun += ((p0[0] + p0[1]) + (p0[2] + p0[3])) + ((p1[0] + p1[1]) + (p1[2] + p1[3]))
              + ((p2[0] + p2[1]) + (p2[2] + p2[3])) + ((p3[0] + p3[1]) + (p3[2] + p3[3]));

        uint4v ua, ub;
        asm("v_cvt_pk_bf16_f32 %0, %1, %2" : "=v"(ua[0]) : "v"(p0[0]), "v"(p0[1]));
        asm("v_cvt_pk_bf16_f32 %0, %1, %2" : "=v"(ua[1]) : "v"(p0[2]), "v"(p0[3]));
        asm("v_cvt_pk_bf16_f32 %0, %1, %2" : "=v"(ua[2]) : "v"(p1[0]), "v"(p1[1]));
        asm("v_cvt_pk_bf16_f32 %0, %1, %2" : "=v"(ua[3]) : "v"(p1[2]), "v"(p1[3]));
        asm("v_cvt_pk_bf16_f32 %0, %1, %2" : "=v"(ub[0]) : "v"(p2[0]), "v"(p2[1]));
        asm("v_cvt_pk_bf16_f32 %0, %1, %2" : "=v"(ub[1]) : "v"(p2[2]), "v"(p2[3]));
        asm("v_cvt_pk_bf16_f32 %0, %1, %2" : "=v"(ub[2]) : "v"(p3[0]), "v"(p3[1]));
        asm("v_cvt_pk_bf16_f32 %0, %1, %2" : "=v"(ub[3]) : "v"(p3[2]), "v"(p3[3]));
        short8 pba = *(short8*)&ua;        // keys kvb..kvb+31  (B-frag k=lg*8+j)
        short8 pbb = *(short8*)&ub;        // keys kvb+32..kvb+63

        // ---- PV accumulate
        o[0] = __builtin_amdgcn_mfma_f32_16x16x32_bf16(vf00, pba, o[0], 0, 0, 0);
        o[1] = __builtin_amdgcn_mfma_f32_16x16x32_bf16(vf10, pba, o[1], 0, 0, 0);
        o[2] = __builtin_amdgcn_mfma_f32_16x16x32_bf16(vf20, pba, o[2], 0, 0, 0);
        o[3] = __builtin_amdgcn_mfma_f32_16x16x32_bf16(vf30, pba, o[3], 0, 0, 0);
        o[0] = __builtin_amdgcn_mfma_f32_16x16x32_bf16(vf01, pbb, o[0], 0, 0, 0);
        o[1] = __builtin_amdgcn_mfma_f32_16x16x32_bf16(vf11, pbb, o[1], 0, 0, 0);
        o[2] = __builtin_amdgcn_mfma_f32_16x16x32_bf16(vf21, pbb, o[2], 0, 0, 0);
        o[3] = __builtin_amdgcn_mfma_f32_16x16x32_bf16(vf31, pbb, o[3], 0, 0, 0);
    }

    // ---- write partials: o[nt][r] = O[q=lr][d = nt*16+lg*4+r], per-lane (m,l)
    #pragma unroll
    for (int nt = 0; nt < 4; ++nt)
        #pragma unroll
        for (int r = 0; r < 4; ++r)
            lds_o[w][lr][nt * 16 + lg * 4 + r] = o[nt][r];
    lds_ml[w][lg][lr][0] = mrun;
    lds_ml[w][lg][lr][1] = lrun;
    __syncthreads();

    // ---- merge 32 partials (8 waves x 4 lane-groups): 512 thr, 16 rows x 32 col-pairs
    const int row = tid >> 5;
    const int c2  = (tid & 31) * 2;
    const int lgc = (c2 >> 2) & 3;         // lane-group owning this d-column
    float M = -1e30f;
    #pragma unroll
    for (int ww = 0; ww < 8; ++ww)
        #pragma unroll
        for (int g = 0; g < 4; ++g)
            M = fmaxf(M, lds_ml[ww][g][row][0]);
    float L = 0.f, a0 = 0.f, a1 = 0.f;
    #pragma unroll
    for (int ww = 0; ww < 8; ++ww) {
        #pragma unroll
        for (int g = 0; g < 4; ++g)
            L += exp2f(lds_ml[ww][g][row][0] - M) * lds_ml[ww][g][row][1];
        float wt = exp2f(lds_ml[ww][lgc][row][0] - M);
        a0 += wt * lds_o[ww][row][c2];
        a1 += wt * lds_o[ww][row][c2 + 1];
    }
    float invL = 1.0f / L;
    float2 res;
    res.x = a0 * invL;
    res.y = a1 * invL;
    *(float2*)(out + ((size_t)b * SEQ + qbase + row) * HD + c2) = res;
}

// ---------------------------------------------------------------------------
extern "C" void kernel_launch(void* const* d_in, const int* in_sizes, int n_in,
                              void* d_out, int out_size, void* d_ws, size_t ws_size,
                              hipStream_t stream) {
    const float* H  = (const float*)d_in[0];
    const float* Wq = (const float*)d_in[1];
    const float* Wk = (const float*)d_in[2];
    const float* Wv = (const float*)d_in[3];
    float* out = (float*)d_out;

    // workspace layout (bf16): Qb[16384*64] | Kb[16384*64] | Vt[4][64][4096] | Wt[3][64][1024]
    unsigned short* Qb = (unsigned short*)d_ws;
    unsigned short* Kb = Qb + (size_t)NB * SEQ * HD;
    unsigned short* Vt = Kb + (size_t)NB * SEQ * HD;
    unsigned short* Wt = Vt + (size_t)NB * SEQ * HD;
    // total = (3*4*4096*64 + 3*64*1024) * 2 bytes ~= 6.4 MB

    wprep_kernel<<<768, 256, 0, stream>>>(Wq, Wk, Wv, Wt);
    qkv_kernel<<<NB * SEQ / 32, 256, 0, stream>>>(H, Wt, Qb, Kb, Vt);
    attn_kernel<<<NB * (SEQ / 16), 512, 0, stream>>>(Qb, Kb, Vt, out);
}

// Round 11
// 113.841 us; speedup vs baseline: 1.0011x; 1.0011x over previous
//
#include <hip/hip_runtime.h>
#include <hip/hip_bf16.h>
#include <stdint.h>

#define SEQ 4096
#define EMB 1024
#define HD  64
#define NB  4

typedef __attribute__((ext_vector_type(8))) short short8;   // 8 x bf16 (4 VGPRs)
typedef __attribute__((ext_vector_type(4))) float f32x4;
typedef __attribute__((ext_vector_type(4))) unsigned int uint4v;

// RNE float -> bf16 bits (no NaN inputs here)
static __device__ __forceinline__ unsigned short f2bf(float f) {
    unsigned int u = __float_as_uint(f);
    u += 0x7fffu + ((u >> 16) & 1u);
    return (unsigned short)(u >> 16);
}

// ---------------------------------------------------------------------------
// Prep: Wt[m][d][e] = bf16(W_m[e][d]),  m in {q,k,v}.  3*64*1024 elements.
// Wq is pre-scaled by log2(e)/sqrt(64) so attn needs no scale multiply.
// ---------------------------------------------------------------------------
__global__ __launch_bounds__(256) void wprep_kernel(
        const float* __restrict__ Wq, const float* __restrict__ Wk,
        const float* __restrict__ Wv, unsigned short* __restrict__ Wt) {
    int idx = blockIdx.x * 256 + threadIdx.x;       // < 3*65536
    int m = idx >> 16;
    int r = idx & 65535;
    int d = r >> 10;
    int e = r & 1023;
    const float* W = (m == 0) ? Wq : (m == 1) ? Wk : Wv;
    float v = W[e * HD + d];
    if (m == 0) v *= 0.18033688011111793f;          // log2(e)/sqrt(64)
    Wt[idx] = f2bf(v);
}

// ---------------------------------------------------------------------------
// QKV projection: 32-row blocks, fused m, 4-wave K-split (256 K each, 8 steps).
// V LAYOUT CHANGE (this round's single variable): V stored as chunked tiles
//   Vt[b][chunk = s>>6][d][64]   (d-stride 128B, chunk-stride 8KB)
// instead of Vt[b][d][s] (d... row stride 8KB -> all 16 rows of a PV fragment
// load hit the SAME L2 channel; that serialization pinned attn at ~70us).
// In-chunk column: p = (s&32) | sigma(t), t = s&31, sigma(t)=((t&12)<<1)|(t&3)|((t&16)>>2).
// ---------------------------------------------------------------------------
__global__ __launch_bounds__(256, 2) void qkv_kernel(
        const float* __restrict__ H, const unsigned short* __restrict__ Wt,
        unsigned short* __restrict__ Qb, unsigned short* __restrict__ Kb,
        unsigned short* __restrict__ Vt) {
    __shared__ float lds_red[2][32][192];   // 48 KB
    const int tid  = threadIdx.x;
    const int wid  = tid >> 6;
    const int lane = tid & 63;
    const int lr = lane & 15, lg = lane >> 4;
    const int rowbase = blockIdx.x * 32;

    const float* __restrict__ a0p = H + (size_t)(rowbase + lr) * EMB + wid * 256 + lg * 8;
    const float* __restrict__ a1p = a0p + 16 * EMB;
    const unsigned short* __restrict__ wb = Wt + wid * 256 + lg * 8;

    f32x4 acc[2][3][4];
    #pragma unroll
    for (int rt = 0; rt < 2; ++rt)
        #pragma unroll
        for (int m = 0; m < 3; ++m)
            #pragma unroll
            for (int nt = 0; nt < 4; ++nt)
                acc[rt][m][nt] = f32x4{0.f, 0.f, 0.f, 0.f};

    f32x4 hA0, hA1, hA2, hA3, hB0, hB1, hB2, hB3;

    auto compute_step = [&](f32x4& h0, f32x4& h1, f32x4& h2, f32x4& h3, int kk) {
        short8 af0, af1;
        #pragma unroll
        for (int j = 0; j < 4; ++j) {
            af0[j]     = (short)f2bf(h0[j]);
            af0[4 + j] = (short)f2bf(h1[j]);
            af1[j]     = (short)f2bf(h2[j]);
            af1[4 + j] = (short)f2bf(h3[j]);
        }
        #pragma unroll
        for (int m = 0; m < 3; ++m) {
            #pragma unroll
            for (int nt = 0; nt < 4; ++nt) {
                short8 bf_ = *(const short8*)(wb + m * 65536 + (nt * 16 + lr) * EMB + kk);
                acc[0][m][nt] = __builtin_amdgcn_mfma_f32_16x16x32_bf16(af0, bf_, acc[0][m][nt], 0, 0, 0);
                acc[1][m][nt] = __builtin_amdgcn_mfma_f32_16x16x32_bf16(af1, bf_, acc[1][m][nt], 0, 0, 0);
            }
        }
    };

    // prologue: load kk=0
    hA0 = *(const f32x4*)(a0p);  hA1 = *(const f32x4*)(a0p + 4);
    hA2 = *(const f32x4*)(a1p);  hA3 = *(const f32x4*)(a1p + 4);

    #pragma unroll
    for (int kko = 0; kko < 4; ++kko) {
        const int kk = kko * 64;
        hB0 = *(const f32x4*)(a0p + kk + 32);  hB1 = *(const f32x4*)(a0p + kk + 36);
        hB2 = *(const f32x4*)(a1p + kk + 32);  hB3 = *(const f32x4*)(a1p + kk + 36);
        compute_step(hA0, hA1, hA2, hA3, kk);
        if (kko < 3) {
            hA0 = *(const f32x4*)(a0p + kk + 64);  hA1 = *(const f32x4*)(a0p + kk + 68);
            hA2 = *(const f32x4*)(a1p + kk + 64);  hA3 = *(const f32x4*)(a1p + kk + 68);
        }
        compute_step(hB0, hB1, hB2, hB3, kk + 32);
    }

    // ---- pairwise cross-wave reduction
    if (wid >= 2) {
        #pragma unroll
        for (int rt = 0; rt < 2; ++rt)
            #pragma unroll
            for (int m = 0; m < 3; ++m)
                #pragma unroll
                for (int nt = 0; nt < 4; ++nt)
                    #pragma unroll
                    for (int r = 0; r < 4; ++r)
                        lds_red[wid - 2][rt * 16 + lg * 4 + r][m * 64 + nt * 16 + lr] = acc[rt][m][nt][r];
    }
    __syncthreads();
    if (wid < 2) {
        #pragma unroll
        for (int rt = 0; rt < 2; ++rt)
            #pragma unroll
            for (int m = 0; m < 3; ++m)
                #pragma unroll
                for (int nt = 0; nt < 4; ++nt)
                    #pragma unroll
                    for (int r = 0; r < 4; ++r)
                        acc[rt][m][nt][r] += lds_red[wid][rt * 16 + lg * 4 + r][m * 64 + nt * 16 + lr];
    }
    __syncthreads();
    if (wid == 1) {
        #pragma unroll
        for (int rt = 0; rt < 2; ++rt)
            #pragma unroll
            for (int m = 0; m < 3; ++m)
                #pragma unroll
                for (int nt = 0; nt < 4; ++nt)
                    #pragma unroll
                    for (int r = 0; r < 4; ++r)
                        lds_red[0][rt * 16 + lg * 4 + r][m * 64 + nt * 16 + lr] = acc[rt][m][nt][r];
    }
    __syncthreads();
    if (wid == 0) {
        #pragma unroll
        for (int rt = 0; rt < 2; ++rt)
            #pragma unroll
            for (int m = 0; m < 3; ++m)
                #pragma unroll
                for (int nt = 0; nt < 4; ++nt)
                    #pragma unroll
                    for (int r = 0; r < 4; ++r) {
                        int row = rt * 16 + lg * 4 + r;
                        int col = m * 64 + nt * 16 + lr;
                        lds_red[0][row][col] += acc[rt][m][nt][r];
                    }
    }
    __syncthreads();

    // ---- parallel epilogue: 256 threads store from lds_red[0]
    {
        const int row = tid >> 3;            // 0..31
        const int d0  = (tid & 7) * 8;       // 0,8,...,56
        const size_t grow = (size_t)(rowbase + row);
        short8 uq, uk;
        #pragma unroll
        for (int j = 0; j < 8; ++j) {
            uq[j] = (short)f2bf(lds_red[0][row][d0 + j]);
            uk[j] = (short)f2bf(lds_red[0][row][64 + d0 + j]);
        }
        *(short8*)(Qb + grow * HD + d0) = uq;
        *(short8*)(Kb + grow * HD + d0) = uk;
    }
    {
        const int d  = tid >> 2;             // 0..63
        const int j  = tid & 3;
        const int b  = rowbase >> 12;
        const int sl = rowbase & (SEQ - 1);
        // chunked V layout: base of this block's half-chunk for row d
        unsigned short* vrow = Vt + (((size_t)b * 64 + (sl >> 6)) * 64 + d) * 64 + (sl & 32);
        #pragma unroll
        for (int k4 = 0; k4 < 4; ++k4) {
            int t0 = j * 2 + k4 * 8;         // even t in 0..30
            int p0 = ((t0 & 12) << 1) | (t0 & 3) | ((t0 & 16) >> 2);
            unsigned int val = (unsigned int)f2bf(lds_red[0][t0][128 + d])
                             | ((unsigned int)f2bf(lds_red[0][t0 + 1][128 + d]) << 16);
            *(unsigned int*)(vrow + p0) = val;
        }
    }
}

// ---------------------------------------------------------------------------
// Flash attention, causal, split-K within a block, SWAPPED QK^T, KVBLK=64.
// V now read from chunked tiles Vt[b][it][d][64] (d-stride 128B) — PV
// fragment loads spread across L2 channels instead of hammering one.
// PER-LANE softmax state (zero cross-lane ops in loop); 8x4 partial merge.
// Defer-max THR=8 (exp2 domain); Q pre-scaled in wprep; cvt_pk P packing.
// ---------------------------------------------------------------------------
__global__ __launch_bounds__(512, 4) void attn_kernel(
        const unsigned short* __restrict__ Qb, const unsigned short* __restrict__ Kb,
        const unsigned short* __restrict__ Vt, float* __restrict__ out) {
    __shared__ float lds_o[8][16][65];     // 33.3 KB partials (padded)
    __shared__ float lds_ml[8][4][16][2];  // 4 KB per-(wave,lanegroup) m,l
    const int tid  = threadIdx.x;
    const int w    = tid >> 6;
    const int lane = tid & 63;
    const int lr = lane & 15, lg = lane >> 4;

    const int bid  = blockIdx.x;
    const int xcd  = bid & 7;              // dispatch round-robins XCDs
    const int slot = bid >> 3;             // 0..127 within this XCD
    const int b    = xcd & 3;              // batch pinned to XCD
    const int pz   = slot & 31, hh = slot >> 5;
    const int qtl  = (hh << 5) | ((hh & 1) ? (31 - pz) : pz);  // per-CU balance
    const int qt   = (qtl << 1) | (xcd >> 2);
    const int qbase = qt * 16;

    const unsigned short* __restrict__ Qp = Qb + ((size_t)b * SEQ + qbase) * HD;
    const unsigned short* __restrict__ Kp = Kb + (size_t)b * SEQ * HD;
    const unsigned short* __restrict__ Vp = Vt + (size_t)b * (SEQ / 64) * HD * 64;

    short8 qf0 = *(const short8*)(Qp + lr * HD +      lg * 8);
    short8 qf1 = *(const short8*)(Qp + lr * HD + 32 + lg * 8);

    f32x4 o[4];
    #pragma unroll
    for (int nt = 0; nt < 4; ++nt) o[nt] = f32x4{0.f, 0.f, 0.f, 0.f};
    float mrun = 0.f;                       // per-lane running max (exp2 domain)
    float lrun = 0.f;

    const int total64 = (qbase + 79) >> 6;  // ceil((qbase+16)/64) chunks

    for (int it = w; it < total64; it += 8) {
        const int kvb = it * 64;
        const unsigned short* kp = Kp + (size_t)(kvb + lr) * HD + lg * 8;
        const unsigned short* vp = Vp + ((size_t)it * 64 + lr) * 64 + lg * 8;

        // ---- issue ALL 16 loads up-front (one latency round)
        short8 k00 = *(const short8*)(kp);
        short8 k01 = *(const short8*)(kp + 32);
        short8 k10 = *(const short8*)(kp + 16 * HD);
        short8 k11 = *(const short8*)(kp + 16 * HD + 32);
        short8 k20 = *(const short8*)(kp + 32 * HD);
        short8 k21 = *(const short8*)(kp + 32 * HD + 32);
        short8 k30 = *(const short8*)(kp + 48 * HD);
        short8 k31 = *(const short8*)(kp + 48 * HD + 32);
        short8 vf00 = *(const short8*)(vp);
        short8 vf01 = *(const short8*)(vp + 32);
        short8 vf10 = *(const short8*)(vp + 16 * 64);
        short8 vf11 = *(const short8*)(vp + 16 * 64 + 32);
        short8 vf20 = *(const short8*)(vp + 32 * 64);
        short8 vf21 = *(const short8*)(vp + 32 * 64 + 32);
        short8 vf30 = *(const short8*)(vp + 48 * 64);
        short8 vf31 = *(const short8*)(vp + 48 * 64 + 32);

        // ---- QK^T (swapped): s_t[q] for keys kvb + t*16 + lg*4 + r
        f32x4 s0 = f32x4{0.f, 0.f, 0.f, 0.f};
        f32x4 s1 = f32x4{0.f, 0.f, 0.f, 0.f};
        f32x4 s2 = f32x4{0.f, 0.f, 0.f, 0.f};
        f32x4 s3 = f32x4{0.f, 0.f, 0.f, 0.f};
        s0 = __builtin_amdgcn_mfma_f32_16x16x32_bf16(k00, qf0, s0, 0, 0, 0);
        s0 = __builtin_amdgcn_mfma_f32_16x16x32_bf16(k01, qf1, s0, 0, 0, 0);
        s1 = __builtin_amdgcn_mfma_f32_16x16x32_bf16(k10, qf0, s1, 0, 0, 0);
        s1 = __builtin_amdgcn_mfma_f32_16x16x32_bf16(k11, qf1, s1, 0, 0, 0);
        s2 = __builtin_amdgcn_mfma_f32_16x16x32_bf16(k20, qf0, s2, 0, 0, 0);
        s2 = __builtin_amdgcn_mfma_f32_16x16x32_bf16(k21, qf1, s2, 0, 0, 0);
        s3 = __builtin_amdgcn_mfma_f32_16x16x32_bf16(k30, qf0, s3, 0, 0, 0);
        s3 = __builtin_amdgcn_mfma_f32_16x16x32_bf16(k31, qf1, s3, 0, 0, 0);

        if (kvb + 63 > qbase) {            // chunk touches the diagonal
            const int qg = qbase + lr;
            #pragma unroll
            for (int r = 0; r < 4; ++r) {
                int ky = kvb + lg * 4 + r;
                if (ky      > qg) s0[r] = -1e30f;
                if (ky + 16 > qg) s1[r] = -1e30f;
                if (ky + 32 > qg) s2[r] = -1e30f;
                if (ky + 48 > qg) s3[r] = -1e30f;
            }
        }

        // ---- per-lane max over this lane's 16 keys (no cross-lane ops)
        float m01 = fmaxf(fmaxf(s0[0], s0[1]), fmaxf(s0[2], s0[3]));
        float m23 = fmaxf(fmaxf(s1[0], s1[1]), fmaxf(s1[2], s1[3]));
        float m45 = fmaxf(fmaxf(s2[0], s2[1]), fmaxf(s2[2], s2[3]));
        float m67 = fmaxf(fmaxf(s3[0], s3[1]), fmaxf(s3[2], s3[3]));
        float mx = fmaxf(fmaxf(m01, m23), fmaxf(m45, m67));

        // defer-max: rescale only when some lane's max grew by more than 8
        if (!__all(mx <= mrun + 8.f)) {
            float mnew = fmaxf(mrun, mx);
            float f = exp2f(mrun - mnew);
            mrun = mnew;
            lrun *= f;
            #pragma unroll
            for (int nt = 0; nt < 4; ++nt) o[nt] *= f;
        }

        // ---- P = exp2(s - mrun), pack pairs with v_cvt_pk_bf16_f32
        float p0[4], p1[4], p2[4], p3[4];
        #pragma unroll
        for (int r = 0; r < 4; ++r) {
            p0[r] = exp2f(s0[r] - mrun);
            p1[r] = exp2f(s1[r] - mrun);
            p2[r] = exp2f(s2[r] - mrun);
            p3[r] = exp2f(s3[r] - mrun);
        }
        lrun += ((p0[0] + p0[1]) + (p0[2] + p0[3])) + ((p1[0] + p1[1]) + (p1[2] + p1[3]))
              + ((p2[0] + p2[1]) + (p2[2] + p2[3])) + ((p3[0] + p3[1]) + (p3[2] + p3[3]));

        uint4v ua, ub;
        asm("v_cvt_pk_bf16_f32 %0, %1, %2" : "=v"(ua[0]) : "v"(p0[0]), "v"(p0[1]));
        asm("v_cvt_pk_bf16_f32 %0, %1, %2" : "=v"(ua[1]) : "v"(p0[2]), "v"(p0[3]));
        asm("v_cvt_pk_bf16_f32 %0, %1, %2" : "=v"(ua[2]) : "v"(p1[0]), "v"(p1[1]));
        asm("v_cvt_pk_bf16_f32 %0, %1, %2" : "=v"(ua[3]) : "v"(p1[2]), "v"(p1[3]));
        asm("v_cvt_pk_bf16_f32 %0, %1, %2" : "=v"(ub[0]) : "v"(p2[0]), "v"(p2[1]));
        asm("v_cvt_pk_bf16_f32 %0, %1, %2" : "=v"(ub[1]) : "v"(p2[2]), "v"(p2[3]));
        asm("v_cvt_pk_bf16_f32 %0, %1, %2" : "=v"(ub[2]) : "v"(p3[0]), "v"(p3[1]));
        asm("v_cvt_pk_bf16_f32 %0, %1, %2" : "=v"(ub[3]) : "v"(p3[2]), "v"(p3[3]));
        short8 pba = *(short8*)&ua;        // keys kvb..kvb+31  (B-frag k=lg*8+j)
        short8 pbb = *(short8*)&ub;        // keys kvb+32..kvb+63

        // ---- PV accumulate
        o[0] = __builtin_amdgcn_mfma_f32_16x16x32_bf16(vf00, pba, o[0], 0, 0, 0);
        o[1] = __builtin_amdgcn_mfma_f32_16x16x32_bf16(vf10, pba, o[1], 0, 0, 0);
        o[2] = __builtin_amdgcn_mfma_f32_16x16x32_bf16(vf20, pba, o[2], 0, 0, 0);
        o[3] = __builtin_amdgcn_mfma_f32_16x16x32_bf16(vf30, pba, o[3], 0, 0, 0);
        o[0] = __builtin_amdgcn_mfma_f32_16x16x32_bf16(vf01, pbb, o[0], 0, 0, 0);
        o[1] = __builtin_amdgcn_mfma_f32_16x16x32_bf16(vf11, pbb, o[1], 0, 0, 0);
        o[2] = __builtin_amdgcn_mfma_f32_16x16x32_bf16(vf21, pbb, o[2], 0, 0, 0);
        o[3] = __builtin_amdgcn_mfma_f32_16x16x32_bf16(vf31, pbb, o[3], 0, 0, 0);
    }

    // ---- write partials: o[nt][r] = O[q=lr][d = nt*16+lg*4+r], per-lane (m,l)
    #pragma unroll
    for (int nt = 0; nt < 4; ++nt)
        #pragma unroll
        for (int r = 0; r < 4; ++r)
            lds_o[w][lr][nt * 16 + lg * 4 + r] = o[nt][r];
    lds_ml[w][lg][lr][0] = mrun;
    lds_ml[w][lg][lr][1] = lrun;
    __syncthreads();

    // ---- merge 32 partials (8 waves x 4 lane-groups): 512 thr, 16 rows x 32 col-pairs
    const int row = tid >> 5;
    const int c2  = (tid & 31) * 2;
    const int lgc = (c2 >> 2) & 3;         // lane-group owning this d-column
    float M = -1e30f;
    #pragma unroll
    for (int ww = 0; ww < 8; ++ww)
        #pragma unroll
        for (int g = 0; g < 4; ++g)
            M = fmaxf(M, lds_ml[ww][g][row][0]);
    float L = 0.f, a0 = 0.f, a1 = 0.f;
    #pragma unroll
    for (int ww = 0; ww < 8; ++ww) {
        #pragma unroll
        for (int g = 0; g < 4; ++g)
            L += exp2f(lds_ml[ww][g][row][0] - M) * lds_ml[ww][g][row][1];
        float wt = exp2f(lds_ml[ww][lgc][row][0] - M);
        a0 += wt * lds_o[ww][row][c2];
        a1 += wt * lds_o[ww][row][c2 + 1];
    }
    float invL = 1.0f / L;
    float2 res;
    res.x = a0 * invL;
    res.y = a1 * invL;
    *(float2*)(out + ((size_t)b * SEQ + qbase + row) * HD + c2) = res;
}

// ---------------------------------------------------------------------------
extern "C" void kernel_launch(void* const* d_in, const int* in_sizes, int n_in,
                              void* d_out, int out_size, void* d_ws, size_t ws_size,
                              hipStream_t stream) {
    const float* H  = (const float*)d_in[0];
    const float* Wq = (const float*)d_in[1];
    const float* Wk = (const float*)d_in[2];
    const float* Wv = (const float*)d_in[3];
    float* out = (float*)d_out;

    // workspace layout (bf16): Qb[16384*64] | Kb[16384*64] | Vt[4][64][64][64] | Wt[3][64][1024]
    unsigned short* Qb = (unsigned short*)d_ws;
    unsigned short* Kb = Qb + (size_t)NB * SEQ * HD;
    unsigned short* Vt = Kb + (size_t)NB * SEQ * HD;
    unsigned short* Wt = Vt + (size_t)NB * SEQ * HD;
    // total = (3*4*4096*64 + 3*64*1024) * 2 bytes ~= 6.4 MB

    wprep_kernel<<<768, 256, 0, stream>>>(Wq, Wk, Wv, Wt);
    qkv_kernel<<<NB * SEQ / 32, 256, 0, stream>>>(H, Wt, Qb, Kb, Vt);
    attn_kernel<<<NB * (SEQ / 16), 512, 0, stream>>>(Qb, Kb, Vt, out);
}